// Round 5
// baseline (216.621 us; speedup 1.0000x reference)
//
#include <hip/hip_runtime.h>

typedef __attribute__((ext_vector_type(8))) short short8;
typedef __attribute__((ext_vector_type(4))) short short4v;
typedef __attribute__((ext_vector_type(4))) float floatx4;
typedef __attribute__((ext_vector_type(2))) unsigned int uint2v;

#define S_LEN 2048
#define NH 12
#define HD 64
#define EMB 768
#define E3 2304

__device__ __forceinline__ unsigned short f2bf(float f) {
    unsigned int u = __builtin_bit_cast(unsigned int, f);
    u += 0x7FFFu + ((u >> 16) & 1u);   // RNE
    return (unsigned short)(u >> 16);
}

__device__ __forceinline__ unsigned int pack2bf(float a, float b) {
#if __has_builtin(__builtin_amdgcn_cvt_pk_bf16_f32)
    typedef __attribute__((ext_vector_type(2))) short short2v;
    short2v r = __builtin_amdgcn_cvt_pk_bf16_f32(a, b);
    return __builtin_bit_cast(unsigned int, r);
#else
    return (unsigned int)f2bf(a) | ((unsigned int)f2bf(b) << 16);
#endif
}

// async global->LDS, 16B/lane; LDS dest = wave-uniform base + lane*16
__device__ __forceinline__ void gl_lds16(const void* g, void* l) {
    __builtin_amdgcn_global_load_lds(
        (const __attribute__((address_space(1))) unsigned int*)g,
        (__attribute__((address_space(3))) unsigned int*)l, 16, 0, 0);
}

// ------------- fused input conversion: x->bf16, W->Wt bf16 -------------------
__global__ __launch_bounds__(256) void conv_fused(const float* __restrict__ x,
                                                  ushort* __restrict__ xb,
                                                  const float* __restrict__ W,
                                                  ushort* __restrict__ Wt) {
    int tid = threadIdx.x;
    if (blockIdx.x < 6144) {                      // x: 8192*768 / 4 per thread
        int i = (blockIdx.x * 256 + tid) * 4;
        float4 f = *(const float4*)(x + i);
        ushort4 o;
        o.x = f2bf(f.x); o.y = f2bf(f.y); o.z = f2bf(f.z); o.w = f2bf(f.w);
        *(ushort4*)(xb + i) = o;
    } else {                                      // W transpose: 72 x 24 tiles of 32x32
        __shared__ float tile[32][33];
        int b2 = blockIdx.x - 6144;
        int n0 = (b2 % 72) * 32, k0 = (b2 / 72) * 32;
        int tx = tid & 31, ty = tid >> 5;
        for (int i = 0; i < 4; i++)
            tile[ty + i * 8][tx] = W[(size_t)(k0 + ty + i * 8) * E3 + n0 + tx];
        __syncthreads();
        for (int i = 0; i < 4; i++)
            Wt[(size_t)(n0 + ty + i * 8) * EMB + k0 + tx] = f2bf(tile[tx][ty + i * 8]);
    }
}

// ---------------- QKV GEMM: [8192,768] x [768,2304] + bias ----------------
// 128m x 256n tile, BK=64 (12 iters), gl_lds XOR-swizzled staging, 48KB LDS.
// Epilogue via LDS transpose in two n-halves.
__global__ __launch_bounds__(256) void qkv_gemm(const ushort* __restrict__ Xb,
                                                const ushort* __restrict__ Wt,
                                                const float* __restrict__ bias,
                                                ushort* __restrict__ QKb,
                                                ushort* __restrict__ Vt) {
    __shared__ ushort lds[24576];                 // 48KB: A@0 16KB, B@16384B 32KB
    char* ldsb = (char*)lds;
    int tid  = threadIdx.x;
    int wv = tid >> 6, lane = tid & 63;
    int l15 = lane & 15, quad = lane >> 4;
    int r8 = lane >> 3, cc = lane & 7;
    int wm = wv >> 1, wn = wv & 1;
    int m0 = blockIdx.x * 128, n0 = blockIdx.y * 256;

    floatx4 acc[4][8] = {};

    // hoisted staging addresses (bytes); X/Wt row stride = 768 ush = 1536 B
    const char* ag = (const char*)(Xb + (size_t)m0 * EMB)
                   + (wv * 32 + r8) * 1536 + (cc ^ r8) * 16;
    const char* bgp = (const char*)(Wt + (size_t)n0 * EMB)
                   + (wv * 64 + r8) * 1536 + (cc ^ r8) * 16;
    int ast = (wv * 32) * 128;
    int bst = 16384 + (wv * 64) * 128;
    // hoisted fragment offsets
    int afo[2], bfo[2];
    for (int ch = 0; ch < 2; ch++) {
        int sw = ((ch * 4 + quad) ^ (l15 & 7)) * 16;
        afo[ch] = wm * 8192 + l15 * 128 + sw;
        bfo[ch] = 16384 + wn * 16384 + l15 * 128 + sw;
    }

    for (int k0 = 0; k0 < 12; k0++) {
        __syncthreads();
        for (int i = 0; i < 4; i++)
            gl_lds16(ag + i * 12288, ldsb + ast + i * 1024);   // 8 rows x 1536 B
        for (int i = 0; i < 8; i++)
            gl_lds16(bgp + i * 12288, ldsb + bst + i * 1024);
        ag += 128;  bgp += 128;                   // advance 64 k-elems
        __syncthreads();
        for (int ch = 0; ch < 2; ch++) {
            short8 af[4], bf[8];
            for (int mi = 0; mi < 4; mi++)
                af[mi] = *(const short8*)(ldsb + afo[ch] + mi * 2048);
            for (int ni = 0; ni < 8; ni++)
                bf[ni] = *(const short8*)(ldsb + bfo[ch] + ni * 2048);
            for (int mi = 0; mi < 4; mi++)
                for (int ni = 0; ni < 8; ni++)
                    acc[mi][ni] = __builtin_amdgcn_mfma_f32_16x16x32_bf16(
                        af[mi], bf[ni], acc[mi][ni], 0, 0, 0);
        }
    }

    __syncthreads();  // staging reads done; lds reused (128 x 136 stride)
    int seg = n0 / EMB;  // 0=Q, 1=K, 2=V (block-uniform)
    if (seg < 2) {
        float scale = (seg == 0) ? 0.125f : 1.0f;   // fold attention scale into Q
        for (int h = 0; h < 2; h++) {
            if (wn == h) {
                for (int ni = 0; ni < 8; ni++) {
                    int nl = ni * 16 + l15;
                    float bv = bias[n0 + h * 128 + nl];
                    for (int mi = 0; mi < 4; mi++)
                        for (int r = 0; r < 4; r++) {
                            int ml = wm * 64 + mi * 16 + quad * 4 + r;
                            lds[ml * 136 + nl] = f2bf((acc[mi][ni][r] + bv) * scale);
                        }
                }
            }
            __syncthreads();
            int row = tid >> 1, half2 = tid & 1;
            size_t gm = (size_t)(m0 + row);
            for (int i = 0; i < 8; i++) {
                uint4 v = *(const uint4*)&lds[row * 136 + half2 * 64 + i * 8];
                *(uint4*)&QKb[gm * 1536 + n0 + h * 128 + half2 * 64 + i * 8] = v;
            }
            __syncthreads();
        }
    } else {
        for (int h = 0; h < 2; h++) {
            if (wn == h) {
                for (int ni = 0; ni < 8; ni++) {
                    int nl = ni * 16 + l15;
                    float bv = bias[n0 + h * 128 + nl];
                    for (int mi = 0; mi < 4; mi++) {
                        int ml = wm * 64 + mi * 16 + quad * 4;
                        ushort4 p4;
                        p4.x = f2bf(acc[mi][ni][0] + bv);
                        p4.y = f2bf(acc[mi][ni][1] + bv);
                        p4.z = f2bf(acc[mi][ni][2] + bv);
                        p4.w = f2bf(acc[mi][ni][3] + bv);
                        *(ushort4*)&lds[nl * 136 + ml] = p4;
                    }
                }
            }
            __syncthreads();
            int row = tid >> 1, half2 = tid & 1;
            int nn = n0 + h * 128 + row - 1536;
            int hh = nn >> 6, d = nn & 63;
            int bb = m0 >> 11, s0 = m0 & 2047;
            for (int i = 0; i < 8; i++) {
                uint4 v = *(const uint4*)&lds[row * 136 + half2 * 64 + i * 8];
                *(uint4*)&Vt[((size_t)(bb * NH + hh) * HD + d) * S_LEN + s0 + half2 * 64 + i * 8] = v;
            }
            __syncthreads();
        }
    }
}

// ---------------- Attention: ReLU(Q K^T, causal) @ V  (Q pre-scaled) --------
// Static balanced schedule (504 blocks), 1 barrier/stage, cross-item prefetch,
// fully hoisted addressing. Stage = 128 k-cols, double-buffered.
__global__ __launch_bounds__(256) void attn(const ushort* __restrict__ QKb,
                                            const ushort* __restrict__ Vt,
                                            float* __restrict__ out) {
    __shared__ ushort lds[32768];   // 64KB: K buffers @0/16384B; V @32768/49152B
    char* ldsb = (char*)lds;
    int tid = threadIdx.x;
    int w = tid >> 6, lane = tid & 63;
    int l15 = lane & 15, quad = lane >> 4;
    int r8 = lane >> 3, cc = lane & 7;
    int qh = quad >> 1, qlo = quad & 1;
    int rr = lane >> 4;

    // ---- hoisted lane-dependent offsets (loop-invariant) ----
    int kfo[2];
    for (int ch = 0; ch < 2; ch++)
        kfo[ch] = l15 * 128 + ((ch * 4 + quad) ^ (l15 & 7)) * 16;
    int vfo[8];
    for (int t = 0; t < 8; t++)
        vfo[t] = 32768 + l15 * 256 + qlo * 8 + ((2 * t + qh) ^ l15) * 16;
    int rhs[2] = { w * 32 + l15, w * 32 + 16 + l15 };   // causal threshold (qt cancels)
    int kgo = (w * 32 + r8) * 3072 + (cc ^ r8) * 16;    // K staging (QKb row = 3072 B)
    int vgo[4];
    for (int i = 0; i < 4; i++)
        vgo[i] = (w * 16 + i * 4 + rr) * 4096 + (((lane & 15) ^ ((i * 4 + rr) & 15)) * 16);
    int kst = (w * 32) * 128;            // LDS K dst, + i*1024 + p*16384
    int vst = 32768 + (w * 16) * 256;    // LDS V dst, + i*1024 + p*16384

    // ---- static bucket schedule: 504 blocks cover all 768 (qt,bh) items ----
    int b = blockIdx.x;
    int nit, qts[2], bhs[2];
    if (b < 240)      { nit = 1; qts[0] = 15 - b / 48; bhs[0] = b % 48; qts[1] = 0; bhs[1] = 0; }
    else if (b < 480) { int j = b - 240; nit = 2; qts[0] = 10 - j / 48; bhs[0] = j % 48;
                        qts[1] = 1 + j / 48; bhs[1] = j % 48; }
    else              { int j = b - 480; nit = 2; qts[0] = 0; bhs[0] = 2 * j;
                        qts[1] = 0; bhs[1] = 2 * j + 1; }

    const char* kg[2]; const char* vg[2];
    for (int i = 0; i < 2; i++) {
        int bh = bhs[i], bg = bh / NH, h = bh % NH;
        kg[i] = (const char*)(QKb + (size_t)bg * S_LEN * 1536 + 768 + h * 64) + kgo;
        vg[i] = (const char*)(Vt + (size_t)bh * HD * S_LEN);
    }

    auto prefetch = [&](const char* kbase, const char* vbase, int dstP) {
        for (int i = 0; i < 4; i++)
            gl_lds16(kbase + i * 24576, ldsb + dstP * 16384 + kst + i * 1024);
        for (int i = 0; i < 4; i++)
            gl_lds16(vbase + vgo[i], ldsb + dstP * 16384 + vst + i * 1024);
    };

    int p = 0;
    prefetch(kg[0], vg[0], 0);
    for (int ii = 0; ii < nit; ii++) {
        int qt = qts[ii];
        int bh = bhs[ii], bg = bh / NH, h = bh % NH;
        const ushort* Qcol = QKb + (size_t)bg * S_LEN * 1536 + h * 64;
        short8 qf[2][2];
        for (int nq = 0; nq < 2; nq++)
            for (int ch = 0; ch < 2; ch++)
                qf[nq][ch] = *(const short8*)(Qcol +
                    (size_t)(qt * 128 + w * 32 + nq * 16 + l15) * 1536 + ch * 32 + quad * 8);

        floatx4 acco[2][4] = {};
        int nst = qt + 1;
        for (int st = 0; st < nst; st++) {
            __syncthreads();                       // sole barrier: buf[p] staged; buf[p^1] free
            if (st + 1 < nst)
                prefetch(kg[ii] + (size_t)(st + 1) * 393216, vg[ii] + (st + 1) * 256, p ^ 1);
            else if (ii + 1 < nit)
                prefetch(kg[ii + 1], vg[ii + 1], p ^ 1);   // next item's stage 0

            bool diag = (st == qt);
            const char* kb = ldsb + p * 16384;

            for (int jsub = 0; jsub < 2; jsub++) {
                // S^T = K·Q^T : 64 k-rows x 32 q, K(d)=64
                floatx4 stc[4][2] = {};
                for (int ch = 0; ch < 2; ch++) {
                    short8 kf[4];
                    for (int mk = 0; mk < 4; mk++)
                        kf[mk] = *(const short8*)(kb + kfo[ch] + jsub * 8192 + mk * 2048);
                    for (int mk = 0; mk < 4; mk++)
                        for (int nq = 0; nq < 2; nq++)
                            stc[mk][nq] = __builtin_amdgcn_mfma_f32_16x16x32_bf16(
                                kf[mk], qf[nq][ch], stc[mk][nq], 0, 0, 0);
                }

                // ReLU + causal mask + pack (PV A-frag layout)
                unsigned int pk[4][2][2];
                for (int mk = 0; mk < 4; mk++) {
                    for (int nq = 0; nq < 2; nq++) {
                        float e[4];
                        for (int r = 0; r < 4; r++)
                            e[r] = fmaxf(stc[mk][nq][r], 0.0f);
                        if (diag) {
                            int kl = jsub * 64 + mk * 16 + quad * 4;
                            for (int r = 0; r < 4; r++)
                                if (kl + r > rhs[nq]) e[r] = 0.0f;
                        }
                        pk[mk][nq][0] = pack2bf(e[0], e[1]);
                        pk[mk][nq][1] = pack2bf(e[2], e[3]);
                    }
                }

                // O += P·V via 16x16x16 (A in-register, B = V from LDS)
                for (int mk = 0; mk < 4; mk++) {
                    int t = jsub * 4 + mk;
                    short4v vf[4];
                    for (int ni = 0; ni < 4; ni++)
                        vf[ni] = *(const short4v*)(kb + vfo[t] + ni * 4096);
                    for (int mi = 0; mi < 2; mi++) {
                        short4v a = __builtin_bit_cast(short4v,
                                     (uint2v){pk[mk][mi][0], pk[mk][mi][1]});
                        for (int ni = 0; ni < 4; ni++)
                            acco[mi][ni] = __builtin_amdgcn_mfma_f32_16x16x16bf16_1k(
                                a, vf[ni], acco[mi][ni], 0, 0, 0);
                    }
                }
            }
            p ^= 1;
        }

        // epilogue: out[b][s][h*64+d] fp32 (overlaps next item's prefetch)
        for (int mi = 0; mi < 2; mi++) {
            for (int ni = 0; ni < 4; ni++) {
                int d = ni * 16 + l15;
                for (int r = 0; r < 4; r++) {
                    int s = qt * 128 + w * 32 + mi * 16 + quad * 4 + r;
                    out[((size_t)bg * S_LEN + s) * EMB + h * 64 + d] = acco[mi][ni][r];
                }
            }
        }
    }
}

extern "C" void kernel_launch(void* const* d_in, const int* in_sizes, int n_in,
                              void* d_out, int out_size, void* d_ws, size_t ws_size,
                              hipStream_t stream) {
    const float* x    = (const float*)d_in[0];   // [4,2048,768]
    const float* W    = (const float*)d_in[1];   // [768,2304]
    const float* bias = (const float*)d_in[2];   // [2304]
    float* out = (float*)d_out;                  // [4,2048,768] fp32

    char* ws = (char*)d_ws;
    const size_t SZ_X  = (size_t)8192 * EMB * 2;
    const size_t SZ_W  = (size_t)E3 * EMB * 2;
    const size_t SZ_QK = (size_t)8192 * 1536 * 2;
    ushort* Xb  = (ushort*)(ws);
    ushort* Wt  = (ushort*)(ws + SZ_X);
    ushort* QKb = (ushort*)(ws + SZ_X + SZ_W);
    ushort* Vt  = (ushort*)(ws + SZ_X + SZ_W + SZ_QK);

    conv_fused<<<dim3(6144 + 1728), dim3(256), 0, stream>>>(x, Xb, W, Wt);
    qkv_gemm<<<dim3(64, 9), dim3(256), 0, stream>>>(Xb, Wt, bias, QKb, Vt);
    attn<<<dim3(504), dim3(256), 0, stream>>>(QKb, Vt, out);
}

// Round 6
// 181.516 us; speedup vs baseline: 1.1934x; 1.1934x over previous
//
#include <hip/hip_runtime.h>

typedef __attribute__((ext_vector_type(8))) short short8;
typedef __attribute__((ext_vector_type(4))) short short4v;
typedef __attribute__((ext_vector_type(4))) float floatx4;
typedef __attribute__((ext_vector_type(2))) unsigned int uint2v;

#define S_LEN 2048
#define NH 12
#define HD 64
#define EMB 768
#define E3 2304

__device__ __forceinline__ unsigned short f2bf(float f) {
    unsigned int u = __builtin_bit_cast(unsigned int, f);
    u += 0x7FFFu + ((u >> 16) & 1u);   // RNE
    return (unsigned short)(u >> 16);
}

__device__ __forceinline__ unsigned int pack2bf(float a, float b) {
#if __has_builtin(__builtin_amdgcn_cvt_pk_bf16_f32)
    typedef __attribute__((ext_vector_type(2))) short short2v;
    short2v r = __builtin_amdgcn_cvt_pk_bf16_f32(a, b);
    return __builtin_bit_cast(unsigned int, r);
#else
    return (unsigned int)f2bf(a) | ((unsigned int)f2bf(b) << 16);
#endif
}

// async global->LDS, 16B/lane; LDS dest = wave-uniform base + lane*16
__device__ __forceinline__ void gl_lds16(const void* g, void* l) {
    __builtin_amdgcn_global_load_lds(
        (const __attribute__((address_space(1))) unsigned int*)g,
        (__attribute__((address_space(3))) unsigned int*)l, 16, 0, 0);
}

// ------------- fused input conversion: x->bf16, W->Wt bf16 -------------------
__global__ __launch_bounds__(256) void conv_fused(const float* __restrict__ x,
                                                  ushort* __restrict__ xb,
                                                  const float* __restrict__ W,
                                                  ushort* __restrict__ Wt) {
    int tid = threadIdx.x;
    if (blockIdx.x < 6144) {                      // x: 8192*768 / 4 per thread
        int i = (blockIdx.x * 256 + tid) * 4;
        float4 f = *(const float4*)(x + i);
        ushort4 o;
        o.x = f2bf(f.x); o.y = f2bf(f.y); o.z = f2bf(f.z); o.w = f2bf(f.w);
        *(ushort4*)(xb + i) = o;
    } else {                                      // W transpose: 72 x 24 tiles of 32x32
        __shared__ float tile[32][33];
        int b2 = blockIdx.x - 6144;
        int n0 = (b2 % 72) * 32, k0 = (b2 / 72) * 32;
        int tx = tid & 31, ty = tid >> 5;
        for (int i = 0; i < 4; i++)
            tile[ty + i * 8][tx] = W[(size_t)(k0 + ty + i * 8) * E3 + n0 + tx];
        __syncthreads();
        for (int i = 0; i < 4; i++)
            Wt[(size_t)(n0 + ty + i * 8) * EMB + k0 + tx] = f2bf(tile[tx][ty + i * 8]);
    }
}

// ---------------- QKV GEMM: [8192,768] x [768,2304] + bias ----------------
// 128x128 tile (the measured sweet spot), BK=64 (12 iters), gl_lds XOR-swizzled
// staging, hoisted addressing, LDS-transpose coalesced epilogue.
__global__ __launch_bounds__(256) void qkv_gemm(const ushort* __restrict__ Xb,
                                                const ushort* __restrict__ Wt,
                                                const float* __restrict__ bias,
                                                ushort* __restrict__ QKb,
                                                ushort* __restrict__ Vt) {
    __shared__ ushort lds[16896];                 // 33792 B: staging A@0,B@16384 | epi 128x132
    char* ldsb = (char*)lds;
    int tid  = threadIdx.x;
    int wv = tid >> 6, lane = tid & 63;
    int l15 = lane & 15, quad = lane >> 4;
    int r8 = lane >> 3, cc = lane & 7;
    int wm = wv >> 1, wn = wv & 1;
    int m0 = blockIdx.x * 128, n0 = blockIdx.y * 128;

    floatx4 acc[4][4] = {};

    // hoisted staging addresses (bytes); X/Wt row stride = 1536 B
    const char* ag = (const char*)(Xb + (size_t)m0 * EMB)
                   + (wv * 32 + r8) * 1536 + (cc ^ r8) * 16;
    const char* bgp = (const char*)(Wt + (size_t)n0 * EMB)
                   + (wv * 32 + r8) * 1536 + (cc ^ r8) * 16;
    int ast = (wv * 32) * 128;
    int bst = 16384 + (wv * 32) * 128;
    // hoisted fragment offsets
    int afo[2], bfo[2];
    for (int ch = 0; ch < 2; ch++) {
        int sw = ((ch * 4 + quad) ^ (l15 & 7)) * 16;
        afo[ch] = wm * 8192 + l15 * 128 + sw;
        bfo[ch] = 16384 + wn * 8192 + l15 * 128 + sw;
    }

    for (int k0 = 0; k0 < 12; k0++) {
        __syncthreads();
        for (int i = 0; i < 4; i++) {
            gl_lds16(ag + i * 12288, ldsb + ast + i * 1024);   // 8 rows x 1536 B
            gl_lds16(bgp + i * 12288, ldsb + bst + i * 1024);
        }
        ag += 128;  bgp += 128;                   // advance 64 k-elems
        __syncthreads();
        for (int ch = 0; ch < 2; ch++) {
            short8 af[4], bf[4];
            for (int mi = 0; mi < 4; mi++)
                af[mi] = *(const short8*)(ldsb + afo[ch] + mi * 2048);
            for (int ni = 0; ni < 4; ni++)
                bf[ni] = *(const short8*)(ldsb + bfo[ch] + ni * 2048);
            for (int mi = 0; mi < 4; mi++)
                for (int ni = 0; ni < 4; ni++)
                    acc[mi][ni] = __builtin_amdgcn_mfma_f32_16x16x32_bf16(
                        af[mi], bf[ni], acc[mi][ni], 0, 0, 0);
        }
    }

    __syncthreads();  // staging reads done; lds reused (128 x 132 stride)
    int seg = n0 / EMB;  // 0=Q, 1=K, 2=V (block-uniform: 6 y-blocks per segment)
    if (seg < 2) {
        float scale = (seg == 0) ? 0.125f : 1.0f;   // fold attention scale into Q
        for (int ni = 0; ni < 4; ni++) {
            int nl = wn * 64 + ni * 16 + l15;
            float bv = bias[n0 + nl];
            for (int mi = 0; mi < 4; mi++)
                for (int r = 0; r < 4; r++) {
                    int ml = wm * 64 + mi * 16 + quad * 4 + r;
                    lds[ml * 132 + nl] = f2bf((acc[mi][ni][r] + bv) * scale);
                }
        }
        __syncthreads();
        int row = tid >> 1, half2 = tid & 1;
        size_t gm = (size_t)(m0 + row);
        for (int i = 0; i < 8; i++) {
            uint4 v = *(const uint4*)&lds[row * 132 + half2 * 64 + i * 8];
            *(uint4*)&QKb[gm * 1536 + n0 + half2 * 64 + i * 8] = v;
        }
    } else {
        for (int ni = 0; ni < 4; ni++) {
            int nl = wn * 64 + ni * 16 + l15;
            float bv = bias[n0 + nl];
            for (int mi = 0; mi < 4; mi++) {
                int ml = wm * 64 + mi * 16 + quad * 4;
                ushort4 p4;
                p4.x = f2bf(acc[mi][ni][0] + bv);
                p4.y = f2bf(acc[mi][ni][1] + bv);
                p4.z = f2bf(acc[mi][ni][2] + bv);
                p4.w = f2bf(acc[mi][ni][3] + bv);
                *(ushort4*)&lds[nl * 132 + ml] = p4;
            }
        }
        __syncthreads();
        int row = tid >> 1, half2 = tid & 1;
        int nn = n0 + row - 1536;
        int hh = nn >> 6, d = nn & 63;
        int bb = m0 >> 11, s0 = m0 & 2047;
        for (int i = 0; i < 8; i++) {
            uint4 v = *(const uint4*)&lds[row * 132 + half2 * 64 + i * 8];
            *(uint4*)&Vt[((size_t)(bb * NH + hh) * HD + d) * S_LEN + s0 + half2 * 64 + i * 8] = v;
        }
    }
}

// ---------------- Attention: ReLU(Q K^T, causal) @ V  (Q pre-scaled) --------
// Static balanced schedule (504 blocks), 1 barrier/stage, cross-item prefetch,
// fully hoisted addressing. Stage = 128 k-cols, double-buffered.
__global__ __launch_bounds__(256) void attn(const ushort* __restrict__ QKb,
                                            const ushort* __restrict__ Vt,
                                            float* __restrict__ out) {
    __shared__ ushort lds[32768];   // 64KB: K buffers @0/16384B; V @32768/49152B
    char* ldsb = (char*)lds;
    int tid = threadIdx.x;
    int w = tid >> 6, lane = tid & 63;
    int l15 = lane & 15, quad = lane >> 4;
    int r8 = lane >> 3, cc = lane & 7;
    int qh = quad >> 1, qlo = quad & 1;
    int rr = lane >> 4;

    // ---- hoisted lane-dependent offsets (loop-invariant) ----
    int kfo[2];
    for (int ch = 0; ch < 2; ch++)
        kfo[ch] = l15 * 128 + ((ch * 4 + quad) ^ (l15 & 7)) * 16;
    int vfo[8];
    for (int t = 0; t < 8; t++)
        vfo[t] = 32768 + l15 * 256 + qlo * 8 + ((2 * t + qh) ^ l15) * 16;
    int rhs[2] = { w * 32 + l15, w * 32 + 16 + l15 };   // causal threshold (qt cancels)
    int kgo = (w * 32 + r8) * 3072 + (cc ^ r8) * 16;    // K staging (QKb row = 3072 B)
    int vgo[4];
    for (int i = 0; i < 4; i++)
        vgo[i] = (w * 16 + i * 4 + rr) * 4096 + (((lane & 15) ^ ((i * 4 + rr) & 15)) * 16);
    int kst = (w * 32) * 128;            // LDS K dst, + i*1024 + p*16384
    int vst = 32768 + (w * 16) * 256;    // LDS V dst, + i*1024 + p*16384

    // ---- static bucket schedule: 504 blocks cover all 768 (qt,bh) items ----
    int b = blockIdx.x;
    int nit, qts[2], bhs[2];
    if (b < 240)      { nit = 1; qts[0] = 15 - b / 48; bhs[0] = b % 48; qts[1] = 0; bhs[1] = 0; }
    else if (b < 480) { int j = b - 240; nit = 2; qts[0] = 10 - j / 48; bhs[0] = j % 48;
                        qts[1] = 1 + j / 48; bhs[1] = j % 48; }
    else              { int j = b - 480; nit = 2; qts[0] = 0; bhs[0] = 2 * j;
                        qts[1] = 0; bhs[1] = 2 * j + 1; }

    const char* kg[2]; const char* vg[2];
    for (int i = 0; i < 2; i++) {
        int bh = bhs[i], bg = bh / NH, h = bh % NH;
        kg[i] = (const char*)(QKb + (size_t)bg * S_LEN * 1536 + 768 + h * 64) + kgo;
        vg[i] = (const char*)(Vt + (size_t)bh * HD * S_LEN);
    }

    auto prefetch = [&](const char* kbase, const char* vbase, int dstP) {
        for (int i = 0; i < 4; i++)
            gl_lds16(kbase + i * 24576, ldsb + dstP * 16384 + kst + i * 1024);
        for (int i = 0; i < 4; i++)
            gl_lds16(vbase + vgo[i], ldsb + dstP * 16384 + vst + i * 1024);
    };

    int p = 0;
    prefetch(kg[0], vg[0], 0);
    for (int ii = 0; ii < nit; ii++) {
        int qt = qts[ii];
        int bh = bhs[ii], bg = bh / NH, h = bh % NH;
        const ushort* Qcol = QKb + (size_t)bg * S_LEN * 1536 + h * 64;
        short8 qf[2][2];
        for (int nq = 0; nq < 2; nq++)
            for (int ch = 0; ch < 2; ch++)
                qf[nq][ch] = *(const short8*)(Qcol +
                    (size_t)(qt * 128 + w * 32 + nq * 16 + l15) * 1536 + ch * 32 + quad * 8);

        floatx4 acco[2][4] = {};
        int nst = qt + 1;
        for (int st = 0; st < nst; st++) {
            __syncthreads();                       // sole barrier: buf[p] staged; buf[p^1] free
            if (st + 1 < nst)
                prefetch(kg[ii] + (size_t)(st + 1) * 393216, vg[ii] + (st + 1) * 256, p ^ 1);
            else if (ii + 1 < nit)
                prefetch(kg[ii + 1], vg[ii + 1], p ^ 1);   // next item's stage 0

            bool diag = (st == qt);
            const char* kb = ldsb + p * 16384;

            for (int jsub = 0; jsub < 2; jsub++) {
                // S^T = K·Q^T : 64 k-rows x 32 q, K(d)=64
                floatx4 stc[4][2] = {};
                for (int ch = 0; ch < 2; ch++) {
                    short8 kf[4];
                    for (int mk = 0; mk < 4; mk++)
                        kf[mk] = *(const short8*)(kb + kfo[ch] + jsub * 8192 + mk * 2048);
                    for (int mk = 0; mk < 4; mk++)
                        for (int nq = 0; nq < 2; nq++)
                            stc[mk][nq] = __builtin_amdgcn_mfma_f32_16x16x32_bf16(
                                kf[mk], qf[nq][ch], stc[mk][nq], 0, 0, 0);
                }

                // ReLU + causal mask + pack (PV A-frag layout)
                unsigned int pk[4][2][2];
                for (int mk = 0; mk < 4; mk++) {
                    for (int nq = 0; nq < 2; nq++) {
                        float e[4];
                        for (int r = 0; r < 4; r++)
                            e[r] = fmaxf(stc[mk][nq][r], 0.0f);
                        if (diag) {
                            int kl = jsub * 64 + mk * 16 + quad * 4;
                            for (int r = 0; r < 4; r++)
                                if (kl + r > rhs[nq]) e[r] = 0.0f;
                        }
                        pk[mk][nq][0] = pack2bf(e[0], e[1]);
                        pk[mk][nq][1] = pack2bf(e[2], e[3]);
                    }
                }

                // O += P·V via 16x16x16 (A in-register, B = V from LDS)
                for (int mk = 0; mk < 4; mk++) {
                    int t = jsub * 4 + mk;
                    short4v vf[4];
                    for (int ni = 0; ni < 4; ni++)
                        vf[ni] = *(const short4v*)(kb + vfo[t] + ni * 4096);
                    for (int mi = 0; mi < 2; mi++) {
                        short4v a = __builtin_bit_cast(short4v,
                                     (uint2v){pk[mk][mi][0], pk[mk][mi][1]});
                        for (int ni = 0; ni < 4; ni++)
                            acco[mi][ni] = __builtin_amdgcn_mfma_f32_16x16x16bf16_1k(
                                a, vf[ni], acco[mi][ni], 0, 0, 0);
                    }
                }
            }
            p ^= 1;
        }

        // epilogue: out[b][s][h*64+d] fp32 (overlaps next item's prefetch)
        for (int mi = 0; mi < 2; mi++) {
            for (int ni = 0; ni < 4; ni++) {
                int d = ni * 16 + l15;
                for (int r = 0; r < 4; r++) {
                    int s = qt * 128 + w * 32 + mi * 16 + quad * 4 + r;
                    out[((size_t)bg * S_LEN + s) * EMB + h * 64 + d] = acco[mi][ni][r];
                }
            }
        }
    }
}

extern "C" void kernel_launch(void* const* d_in, const int* in_sizes, int n_in,
                              void* d_out, int out_size, void* d_ws, size_t ws_size,
                              hipStream_t stream) {
    const float* x    = (const float*)d_in[0];   // [4,2048,768]
    const float* W    = (const float*)d_in[1];   // [768,2304]
    const float* bias = (const float*)d_in[2];   // [2304]
    float* out = (float*)d_out;                  // [4,2048,768] fp32

    char* ws = (char*)d_ws;
    const size_t SZ_X  = (size_t)8192 * EMB * 2;
    const size_t SZ_W  = (size_t)E3 * EMB * 2;
    const size_t SZ_QK = (size_t)8192 * 1536 * 2;
    ushort* Xb  = (ushort*)(ws);
    ushort* Wt  = (ushort*)(ws + SZ_X);
    ushort* QKb = (ushort*)(ws + SZ_X + SZ_W);
    ushort* Vt  = (ushort*)(ws + SZ_X + SZ_W + SZ_QK);

    conv_fused<<<dim3(6144 + 1728), dim3(256), 0, stream>>>(x, Xb, W, Wt);
    qkv_gemm<<<dim3(64, 18), dim3(256), 0, stream>>>(Xb, Wt, bias, QKb, Vt);
    attn<<<dim3(504), dim3(256), 0, stream>>>(QKb, Vt, out);
}